// Round 5
// baseline (435.253 us; speedup 1.0000x reference)
//
#include <hip/hip_runtime.h>
#include <hip/hip_bf16.h>

typedef unsigned short u16;
typedef __attribute__((ext_vector_type(8))) short bf16x8;
typedef __attribute__((ext_vector_type(8))) unsigned short u16x8;
typedef __attribute__((ext_vector_type(4))) float f32x4;

#define NTOK 8192
#define DMODEL 1152
#define NHEAD 16
#define DHEAD 72
#define DPAD 96
#define VROWS 80
#define NQKV 3456

__device__ __forceinline__ u16 f2bf(float f){
  __hip_bfloat16 h = __float2bfloat16(f);
  return *reinterpret_cast<u16*>(&h);
}
__device__ __forceinline__ float bf2f(u16 u){
  union { unsigned int i; float f; } v; v.i = ((unsigned int)u) << 16; return v.f;
}
__device__ __forceinline__ void gload16(const void* g, void* l){
  __builtin_amdgcn_global_load_lds((const __attribute__((address_space(1))) void*)g,
                                   (__attribute__((address_space(3))) void*)l, 16, 0, 0);
}

// ---------------- fp32 -> bf16 convert of hidden_states ----------------
__global__ __launch_bounds__(256) void cvt_x(const float* __restrict__ X, u16* __restrict__ Xb){
  int i = (blockIdx.x * 256 + threadIdx.x) * 8;
  float4 a = *(const float4*)(X + i);
  float4 b = *(const float4*)(X + i + 4);
  u16x8 o;
  o[0]=f2bf(a.x); o[1]=f2bf(a.y); o[2]=f2bf(a.z); o[3]=f2bf(a.w);
  o[4]=f2bf(b.x); o[5]=f2bf(b.y); o[6]=f2bf(b.z); o[7]=f2bf(b.w);
  *(u16x8*)(Xb + i) = o;
}

// ------------- transpose+convert weights: WT[n][k] = W[k][n] -----------
__global__ __launch_bounds__(256) void pack_w(const float* __restrict__ Wq, const float* __restrict__ Wk,
                                              const float* __restrict__ Wv, const float* __restrict__ Wo,
                                              u16* __restrict__ WT){
  __shared__ u16 t[32][33];
  int tx = threadIdx.x & 31, ty = threadIdx.x >> 5;
  int k0 = blockIdx.x * 32, n0 = blockIdx.y * 32;
  int ng = n0 + tx;
  const float* W; int nl;
  if (ng < 1152)      { W = Wq; nl = ng; }
  else if (ng < 2304) { W = Wk; nl = ng - 1152; }
  else if (ng < 3456) { W = Wv; nl = ng - 2304; }
  else                { W = Wo; nl = ng - 3456; }
  #pragma unroll
  for (int i = 0; i < 4; i++)
    t[ty + i*8][tx] = f2bf(W[(size_t)(k0 + ty + i*8) * 1152 + nl]);
  __syncthreads();
  #pragma unroll
  for (int i = 0; i < 4; i++)
    WT[(size_t)(n0 + ty + i*8) * 1152 + k0 + tx] = t[tx][ty + i*8];
}

// ---------------- RoPE cos/sin table: [token][c*18+j] ------------------
__global__ __launch_bounds__(256) void rope_tab(const int* __restrict__ pid,
                                                float* __restrict__ tc, float* __restrict__ ts){
  int i = blockIdx.x * 256 + threadIdx.x;
  if (i >= NTOK * 36) return;
  int tok = i / 36, r = i - tok * 36;
  int c = r / 18, j = r - c * 18;
  float freq = exp2f(-0.7382062433f * (float)j);   // 10000^(-2j/36)
  float ang = (float)pid[tok * 2 + c] * freq;
  float s, co;
  sincosf(ang, &s, &co);
  tc[i] = co; ts[i] = s;
}

// --------- GEMM: C[M][Ncols] = A[M][1152] * Bt[Ncols][1152]^T ----------
// m97-style 128x128 tile, BK=64, global_load_lds w16, XOR chunk swizzle.
// FP32OUT=1 stores float (for d_out, which is the reference's fp32 dtype).
template<int FP32OUT>
__global__ __launch_bounds__(256) void gemm_bt(const u16* __restrict__ A, const u16* __restrict__ Bt,
                                               void* __restrict__ C, int Ncols){
  __shared__ u16 Al[128 * 64];
  __shared__ u16 Bl[128 * 64];
  int tid = threadIdx.x, lane = tid & 63, w = tid >> 6;
  int wr = w >> 1, wc = w & 1, l16 = lane & 15, lq = lane >> 4;
  int m0 = blockIdx.x * 128, n0 = blockIdx.y * 128;
  f32x4 acc[4][4] = {};
  int grow = lane >> 3;
  int gchunk = (lane & 7) ^ grow;                    // pre-swizzled global source
  const char* Abase = (const char*)A  + (size_t)(m0 + grow) * 2304 + gchunk * 16;
  const char* Bbase = (const char*)Bt + (size_t)(n0 + grow) * 2304 + gchunk * 16;
  int sw = l16 & 7;
  for (int kt = 0; kt < 18; ++kt){
    __syncthreads();
    #pragma unroll
    for (int i = 0; i < 4; i++){
      int j = w * 4 + i;
      gload16(Abase + (size_t)j * 8 * 2304 + kt * 128, &Al[j * 512]);
      gload16(Bbase + (size_t)j * 8 * 2304 + kt * 128, &Bl[j * 512]);
    }
    __syncthreads();
    #pragma unroll
    for (int kk = 0; kk < 2; kk++){
      bf16x8 af[4], bfr[4];
      #pragma unroll
      for (int m = 0; m < 4; m++){
        int row = wr * 64 + m * 16 + l16;
        af[m] = *(const bf16x8*)&Al[row * 64 + (((kk * 4 + lq) ^ sw) * 8)];
      }
      #pragma unroll
      for (int n = 0; n < 4; n++){
        int row = wc * 64 + n * 16 + l16;
        bfr[n] = *(const bf16x8*)&Bl[row * 64 + (((kk * 4 + lq) ^ sw) * 8)];
      }
      #pragma unroll
      for (int m = 0; m < 4; m++)
        #pragma unroll
        for (int n = 0; n < 4; n++)
          acc[m][n] = __builtin_amdgcn_mfma_f32_16x16x32_bf16(af[m], bfr[n], acc[m][n], 0, 0, 0);
    }
  }
  #pragma unroll
  for (int m = 0; m < 4; m++)
    #pragma unroll
    for (int n = 0; n < 4; n++)
      #pragma unroll
      for (int r = 0; r < 4; r++){
        int row = m0 + wr * 64 + m * 16 + lq * 4 + r;   // C: row=(lane>>4)*4+reg
        int col = n0 + wc * 64 + n * 16 + l16;          //    col=lane&15
        if (FP32OUT) ((float*)C)[(size_t)row * Ncols + col] = acc[m][n][r];
        else         ((u16*)  C)[(size_t)row * Ncols + col] = f2bf(acc[m][n][r]);
      }
}

// ------------- RMS norm + RoPE + layouts for attention -----------------
// block: 256 tokens x 1 head. Writes Qp/Kp [bh][n][96] (zero-pad), Vt [bh][80][1024].
__global__ __launch_bounds__(256) void rmsrope(const u16* __restrict__ QKV,
    const float* __restrict__ tc, const float* __restrict__ ts,
    const float* __restrict__ qsc, const float* __restrict__ ksc, const float* __restrict__ vsc,
    u16* __restrict__ Qp, u16* __restrict__ Kp, u16* __restrict__ Vt){
  __shared__ u16 vl[72][264];                    // 264 u16 stride: 16B-aligned rows
  int h = blockIdx.y, tid = threadIdx.x;
  int tok = blockIdx.x * 256 + tid;              // global token
  int b = tok >> 10, n = tok & 1023;
  int n0 = (blockIdx.x & 3) * 256;               // local-token base of this block
  int bh = b * NHEAD + h;
  const u16* base = QKV + (size_t)tok * NQKV + h * DHEAD;

  { // ---- V: RMS norm -> LDS (for transpose) ----
    u16x8 vr[9];
    #pragma unroll
    for (int i = 0; i < 9; i++) vr[i] = *(const u16x8*)(base + 2304 + i * 8);
    float ss = 0.f;
    #pragma unroll
    for (int i = 0; i < 9; i++)
      #pragma unroll
      for (int e = 0; e < 8; e++){ float f = bf2f(vr[i][e]); ss += f * f; }
    float rv = rsqrtf(ss * (1.f / 72.f) + 1e-6f);
    #pragma unroll
    for (int i = 0; i < 9; i++)
      #pragma unroll
      for (int e = 0; e < 8; e++){
        int d = i * 8 + e;
        vl[d][tid] = f2bf(bf2f(vr[i][e]) * rv * vsc[d]);
      }
  }
  // ---- Q then K: RMS norm + RoPE ----
  #pragma unroll
  for (int qk = 0; qk < 2; ++qk){
    const u16* src = base + qk * 1152;
    const float* sc = qk ? ksc : qsc;
    u16* dst = qk ? Kp : Qp;
    u16x8 xr[9];
    #pragma unroll
    for (int i = 0; i < 9; i++) xr[i] = *(const u16x8*)(src + i * 8);
    float ss = 0.f;
    #pragma unroll
    for (int i = 0; i < 9; i++)
      #pragma unroll
      for (int e = 0; e < 8; e++){ float f = bf2f(xr[i][e]); ss += f * f; }
    float rs_ = rsqrtf(ss * (1.f / 72.f) + 1e-6f);
    float x[72];
    #pragma unroll
    for (int i = 0; i < 9; i++)
      #pragma unroll
      for (int e = 0; e < 8; e++){ int d = i * 8 + e; x[d] = bf2f(xr[i][e]) * rs_ * sc[d]; }
    #pragma unroll
    for (int c = 0; c < 2; c++)
      #pragma unroll
      for (int j = 0; j < 18; j++){
        float co = tc[(size_t)tok * 36 + c * 18 + j];
        float si = ts[(size_t)tok * 36 + c * 18 + j];
        float x1 = x[c * 36 + j], x2 = x[c * 36 + j + 18];
        x[c * 36 + j]      = x1 * co - x2 * si;   // rotate_half within 36-block
        x[c * 36 + j + 18] = x2 * co + x1 * si;
      }
    size_t off = ((size_t)bh * 1024 + n) * DPAD;
    #pragma unroll
    for (int i = 0; i < 9; i++){
      u16x8 o;
      #pragma unroll
      for (int e = 0; e < 8; e++) o[e] = f2bf(x[i * 8 + e]);
      *(u16x8*)(dst + off + i * 8) = o;
    }
    u16x8 z = {0,0,0,0,0,0,0,0};
    #pragma unroll
    for (int i = 9; i < 12; i++) *(u16x8*)(dst + off + i * 8) = z;  // zero pad 72..95
  }
  __syncthreads();
  // ---- V transpose out: Vt[bh][d][n], rows 72..79 zeroed ----
  u16x8 z = {0,0,0,0,0,0,0,0};
  for (int c = tid; c < VROWS * 32; c += 256){
    int row = c >> 5, seg = c & 31;
    u16x8 v = z;
    if (row < 72) v = *(const u16x8*)&vl[row][seg * 8];
    *(u16x8*)(Vt + ((size_t)bh * VROWS + row) * 1024 + n0 + seg * 8) = v;
  }
}

// -------------------- flash attention, 8 waves x 16 q ------------------
__global__ __launch_bounds__(512) void attn(const u16* __restrict__ Qp, const u16* __restrict__ Kp,
                                            const u16* __restrict__ Vt, u16* __restrict__ AO){
  __shared__ u16 Kl[64][104];        // pad: 208B stride, 2-way max
  __shared__ u16 Vl[VROWS][72];      // 144B stride
  __shared__ u16 Pl[8][16][72];      // per-wave P
  int tid = threadIdx.x, lane = tid & 63, w = tid >> 6;
  int l16 = lane & 15, lq = lane >> 4;
  int bh = blockIdx.y, b = bh >> 4, h = bh & 15;
  int q0 = blockIdx.x * 128;
  const u16* Qb = Qp + (size_t)bh * 1024 * DPAD;
  const u16* Kb = Kp + (size_t)bh * 1024 * DPAD;
  const u16* Vb = Vt + (size_t)bh * VROWS * 1024;

  int qrow = q0 + w * 16 + l16;
  bf16x8 qf[3];
  #pragma unroll
  for (int ks = 0; ks < 3; ks++)
    qf[ks] = *(const bf16x8*)(Qb + (size_t)qrow * DPAD + ks * 32 + lq * 8);

  f32x4 accO[5] = {};
  float mrow[4] = {-1e30f, -1e30f, -1e30f, -1e30f};
  float lrow[4] = {0.f, 0.f, 0.f, 0.f};
  const float scl = 0.1178511302f;   // 72^-0.5

  for (int kv = 0; kv < 16; ++kv){
    __syncthreads();
    for (int c = tid; c < 768; c += 512){          // K tile 64x96
      int row = c / 12, col = c - row * 12;
      *(u16x8*)&Kl[row][col * 8] = *(const u16x8*)(Kb + (size_t)(kv * 64 + row) * DPAD + col * 8);
    }
    for (int c = tid; c < VROWS * 8; c += 512){    // V^T tile 80x64
      int row = c >> 3, seg = c & 7;
      *(u16x8*)&Vl[row][seg * 8] = *(const u16x8*)(Vb + (size_t)row * 1024 + kv * 64 + seg * 8);
    }
    __syncthreads();

    f32x4 accS[4] = {};
    #pragma unroll
    for (int j = 0; j < 4; j++)
      #pragma unroll
      for (int ks = 0; ks < 3; ks++){
        bf16x8 kf = *(const bf16x8*)&Kl[j * 16 + l16][ks * 32 + lq * 8];
        accS[j] = __builtin_amdgcn_mfma_f32_16x16x32_bf16(qf[ks], kf, accS[j], 0, 0, 0);
      }
    float alpha[4], rsum[4];
    #pragma unroll
    for (int r = 0; r < 4; r++){
      float v = fmaxf(fmaxf(accS[0][r], accS[1][r]), fmaxf(accS[2][r], accS[3][r]));
      v = fmaxf(v, __shfl_xor(v, 1)); v = fmaxf(v, __shfl_xor(v, 2));
      v = fmaxf(v, __shfl_xor(v, 4)); v = fmaxf(v, __shfl_xor(v, 8));
      float mn = fmaxf(mrow[r], v * scl);
      alpha[r] = __expf(mrow[r] - mn);
      mrow[r] = mn;
      rsum[r] = 0.f;
    }
    #pragma unroll
    for (int j = 0; j < 4; j++)
      #pragma unroll
      for (int r = 0; r < 4; r++){
        float p = __expf(accS[j][r] * scl - mrow[r]);
        rsum[r] += p;
        Pl[w][lq * 4 + r][j * 16 + l16] = f2bf(p);
      }
    #pragma unroll
    for (int r = 0; r < 4; r++){
      float s = rsum[r];
      s += __shfl_xor(s, 1); s += __shfl_xor(s, 2);
      s += __shfl_xor(s, 4); s += __shfl_xor(s, 8);
      lrow[r] = lrow[r] * alpha[r] + s;
    }
    #pragma unroll
    for (int nf = 0; nf < 5; nf++)
      #pragma unroll
      for (int r = 0; r < 4; r++) accO[nf][r] *= alpha[r];
    #pragma unroll
    for (int ks = 0; ks < 2; ks++){
      bf16x8 pf = *(const bf16x8*)&Pl[w][l16][ks * 32 + lq * 8];
      #pragma unroll
      for (int nf = 0; nf < 5; nf++){
        bf16x8 vf = *(const bf16x8*)&Vl[nf * 16 + l16][ks * 32 + lq * 8];
        accO[nf] = __builtin_amdgcn_mfma_f32_16x16x32_bf16(pf, vf, accO[nf], 0, 0, 0);
      }
    }
  }
  #pragma unroll
  for (int r = 0; r < 4; r++){
    float inv = 1.f / lrow[r];
    int qg = q0 + w * 16 + lq * 4 + r;
    size_t rowoff = ((size_t)(b * 1024 + qg)) * DMODEL + h * DHEAD;
    #pragma unroll
    for (int nf = 0; nf < 5; nf++){
      int d = nf * 16 + l16;
      if (d < 72) AO[rowoff + d] = f2bf(accO[nf][r] * inv);
    }
  }
}

extern "C" void kernel_launch(void* const* d_in, const int* in_sizes, int n_in,
                              void* d_out, int out_size, void* d_ws, size_t ws_size,
                              hipStream_t stream){
  const float* X   = (const float*)d_in[0];
  const int*   pid = (const int*)  d_in[1];
  const float* Wq  = (const float*)d_in[2];
  const float* Wk  = (const float*)d_in[3];
  const float* Wv  = (const float*)d_in[4];
  const float* Wo  = (const float*)d_in[5];
  const float* qsc = (const float*)d_in[6];
  const float* ksc = (const float*)d_in[7];
  const float* vsc = (const float*)d_in[8];
  char* ws = (char*)d_ws;
  u16*   Xb  = (u16*)(ws);                    // 18,874,368
  u16*   WT  = (u16*)(ws + 18874368);         // 10,616,832
  u16*   QKV = (u16*)(ws + 29491200);         // 56,623,104
  u16*   Qp  = (u16*)(ws + 86114304);         // 25,165,824
  u16*   Kp  = (u16*)(ws + 111280128);        // 25,165,824
  u16*   Vt  = (u16*)(ws + 136445952);        // 20,971,520
  float* tc  = (float*)(ws + 157417472);      // 1,179,648
  float* tsn = (float*)(ws + 158597120);      // 1,179,648
  u16*   AO  = QKV;                           // alias: QKV dead after rmsrope

  cvt_x  <<<4608, 256, 0, stream>>>(X, Xb);
  pack_w <<<dim3(36, 144), 256, 0, stream>>>(Wq, Wk, Wv, Wo, WT);
  rope_tab<<<1152, 256, 0, stream>>>(pid, tc, tsn);
  gemm_bt<0><<<dim3(64, 27), 256, 0, stream>>>(Xb, WT, QKV, 3456);
  rmsrope<<<dim3(32, 16), 256, 0, stream>>>(QKV, tc, tsn, qsc, ksc, vsc, Qp, Kp, Vt);
  attn   <<<dim3(8, 128), 512, 0, stream>>>(Qp, Kp, Vt, AO);
  gemm_bt<1><<<dim3(64, 9), 256, 0, stream>>>(AO, WT + (size_t)3456 * 1152, d_out, 1152);
}

// Round 6
// 374.961 us; speedup vs baseline: 1.1608x; 1.1608x over previous
//
#include <hip/hip_runtime.h>
#include <hip/hip_bf16.h>

typedef unsigned short u16;
typedef __attribute__((ext_vector_type(8))) short bf16x8;
typedef __attribute__((ext_vector_type(8))) unsigned short u16x8;
typedef __attribute__((ext_vector_type(4))) float f32x4;

#define NTOK 8192
#define DMODEL 1152
#define NHEAD 16
#define DHEAD 72
#define DPAD 96
#define VROWS 80
#define NQKV 3456

__device__ __forceinline__ u16 f2bf(float f){
  __hip_bfloat16 h = __float2bfloat16(f);
  return *reinterpret_cast<u16*>(&h);
}
__device__ __forceinline__ float bf2f(u16 u){
  union { unsigned int i; float f; } v; v.i = ((unsigned int)u) << 16; return v.f;
}
__device__ __forceinline__ void gload16(const void* g, void* l){
  __builtin_amdgcn_global_load_lds((const __attribute__((address_space(1))) void*)g,
                                   (__attribute__((address_space(3))) void*)l, 16, 0, 0);
}

// ---------------- fp32 -> bf16 convert of hidden_states ----------------
__global__ __launch_bounds__(256) void cvt_x(const float* __restrict__ X, u16* __restrict__ Xb){
  int i = (blockIdx.x * 256 + threadIdx.x) * 8;
  float4 a = *(const float4*)(X + i);
  float4 b = *(const float4*)(X + i + 4);
  u16x8 o;
  o[0]=f2bf(a.x); o[1]=f2bf(a.y); o[2]=f2bf(a.z); o[3]=f2bf(a.w);
  o[4]=f2bf(b.x); o[5]=f2bf(b.y); o[6]=f2bf(b.z); o[7]=f2bf(b.w);
  *(u16x8*)(Xb + i) = o;
}

// ------------- transpose+convert weights: WT[n][k] = W[k][n] -----------
__global__ __launch_bounds__(256) void pack_w(const float* __restrict__ Wq, const float* __restrict__ Wk,
                                              const float* __restrict__ Wv, const float* __restrict__ Wo,
                                              u16* __restrict__ WT){
  __shared__ u16 t[32][33];
  int tx = threadIdx.x & 31, ty = threadIdx.x >> 5;
  int k0 = blockIdx.x * 32, n0 = blockIdx.y * 32;
  int ng = n0 + tx;
  const float* W; int nl;
  if (ng < 1152)      { W = Wq; nl = ng; }
  else if (ng < 2304) { W = Wk; nl = ng - 1152; }
  else if (ng < 3456) { W = Wv; nl = ng - 2304; }
  else                { W = Wo; nl = ng - 3456; }
  #pragma unroll
  for (int i = 0; i < 4; i++)
    t[ty + i*8][tx] = f2bf(W[(size_t)(k0 + ty + i*8) * 1152 + nl]);
  __syncthreads();
  #pragma unroll
  for (int i = 0; i < 4; i++)
    WT[(size_t)(n0 + ty + i*8) * 1152 + k0 + tx] = t[tx][ty + i*8];
}

// ---------------- RoPE cos/sin table: [token][c*18+j] ------------------
__global__ __launch_bounds__(256) void rope_tab(const int* __restrict__ pid,
                                                float* __restrict__ tc, float* __restrict__ ts){
  int i = blockIdx.x * 256 + threadIdx.x;
  if (i >= NTOK * 36) return;
  int tok = i / 36, r = i - tok * 36;
  int c = r / 18, j = r - c * 18;
  float freq = exp2f(-0.7382062433f * (float)j);   // 10000^(-2j/36)
  float ang = (float)pid[tok * 2 + c] * freq;
  float s, co;
  sincosf(ang, &s, &co);
  tc[i] = co; ts[i] = s;
}

// --------- GEMM: C[M][Ncols] = A[M][1152] * Bt[Ncols][1152]^T ----------
// m97-style 128x128 tile, BK=64, global_load_lds w16, XOR chunk swizzle.
// FP32OUT=1 stores float (for d_out, which is the reference's fp32 dtype).
template<int FP32OUT>
__global__ __launch_bounds__(256) void gemm_bt(const u16* __restrict__ A, const u16* __restrict__ Bt,
                                               void* __restrict__ C, int Ncols){
  __shared__ u16 Al[128 * 64];
  __shared__ u16 Bl[128 * 64];
  int tid = threadIdx.x, lane = tid & 63, w = tid >> 6;
  int wr = w >> 1, wc = w & 1, l16 = lane & 15, lq = lane >> 4;
  int m0 = blockIdx.x * 128, n0 = blockIdx.y * 128;
  f32x4 acc[4][4] = {};
  int grow = lane >> 3;
  int gchunk = (lane & 7) ^ grow;                    // pre-swizzled global source
  const char* Abase = (const char*)A  + (size_t)(m0 + grow) * 2304 + gchunk * 16;
  const char* Bbase = (const char*)Bt + (size_t)(n0 + grow) * 2304 + gchunk * 16;
  int sw = l16 & 7;
  for (int kt = 0; kt < 18; ++kt){
    __syncthreads();
    #pragma unroll
    for (int i = 0; i < 4; i++){
      int j = w * 4 + i;
      gload16(Abase + (size_t)j * 8 * 2304 + kt * 128, &Al[j * 512]);
      gload16(Bbase + (size_t)j * 8 * 2304 + kt * 128, &Bl[j * 512]);
    }
    __syncthreads();
    #pragma unroll
    for (int kk = 0; kk < 2; kk++){
      bf16x8 af[4], bfr[4];
      #pragma unroll
      for (int m = 0; m < 4; m++){
        int row = wr * 64 + m * 16 + l16;
        af[m] = *(const bf16x8*)&Al[row * 64 + (((kk * 4 + lq) ^ sw) * 8)];
      }
      #pragma unroll
      for (int n = 0; n < 4; n++){
        int row = wc * 64 + n * 16 + l16;
        bfr[n] = *(const bf16x8*)&Bl[row * 64 + (((kk * 4 + lq) ^ sw) * 8)];
      }
      #pragma unroll
      for (int m = 0; m < 4; m++)
        #pragma unroll
        for (int n = 0; n < 4; n++)
          acc[m][n] = __builtin_amdgcn_mfma_f32_16x16x32_bf16(af[m], bfr[n], acc[m][n], 0, 0, 0);
    }
  }
  #pragma unroll
  for (int m = 0; m < 4; m++)
    #pragma unroll
    for (int n = 0; n < 4; n++)
      #pragma unroll
      for (int r = 0; r < 4; r++){
        int row = m0 + wr * 64 + m * 16 + lq * 4 + r;   // C: row=(lane>>4)*4+reg
        int col = n0 + wc * 64 + n * 16 + l16;          //    col=lane&15
        if (FP32OUT) ((float*)C)[(size_t)row * Ncols + col] = acc[m][n][r];
        else         ((u16*)  C)[(size_t)row * Ncols + col] = f2bf(acc[m][n][r]);
      }
}

// ------------- RMS norm + RoPE + layouts for attention -----------------
// block: 256 tokens x 1 head. Writes Qp/Kp [bh][n][96] (zero-pad), Vt [bh][80][1024].
// Q is pre-scaled by 72^-0.5 * log2(e) so attn computes softmax in base 2.
// Vt row 72 = 1.0 (ones row): PV MFMA then yields the softmax denominator free.
__global__ __launch_bounds__(256) void rmsrope(const u16* __restrict__ QKV,
    const float* __restrict__ tc, const float* __restrict__ ts,
    const float* __restrict__ qsc, const float* __restrict__ ksc, const float* __restrict__ vsc,
    u16* __restrict__ Qp, u16* __restrict__ Kp, u16* __restrict__ Vt){
  __shared__ u16 vl[72][264];                    // 264 u16 stride: 16B-aligned rows
  int h = blockIdx.y, tid = threadIdx.x;
  int tok = blockIdx.x * 256 + tid;              // global token
  int b = tok >> 10, n = tok & 1023;
  int n0 = (blockIdx.x & 3) * 256;               // local-token base of this block
  int bh = b * NHEAD + h;
  const u16* base = QKV + (size_t)tok * NQKV + h * DHEAD;

  { // ---- V: RMS norm -> LDS (for transpose) ----
    u16x8 vr[9];
    #pragma unroll
    for (int i = 0; i < 9; i++) vr[i] = *(const u16x8*)(base + 2304 + i * 8);
    float ss = 0.f;
    #pragma unroll
    for (int i = 0; i < 9; i++)
      #pragma unroll
      for (int e = 0; e < 8; e++){ float f = bf2f(vr[i][e]); ss += f * f; }
    float rv = rsqrtf(ss * (1.f / 72.f) + 1e-6f);
    #pragma unroll
    for (int i = 0; i < 9; i++)
      #pragma unroll
      for (int e = 0; e < 8; e++){
        int d = i * 8 + e;
        vl[d][tid] = f2bf(bf2f(vr[i][e]) * rv * vsc[d]);
      }
  }
  // ---- Q then K: RMS norm + RoPE ----
  #pragma unroll
  for (int qk = 0; qk < 2; ++qk){
    const u16* src = base + qk * 1152;
    const float* sc = qk ? ksc : qsc;
    u16* dst = qk ? Kp : Qp;
    float fold = qk ? 1.0f : 0.17002219f;        // Q *= 72^-0.5 * log2(e)
    u16x8 xr[9];
    #pragma unroll
    for (int i = 0; i < 9; i++) xr[i] = *(const u16x8*)(src + i * 8);
    float ss = 0.f;
    #pragma unroll
    for (int i = 0; i < 9; i++)
      #pragma unroll
      for (int e = 0; e < 8; e++){ float f = bf2f(xr[i][e]); ss += f * f; }
    float rs_ = rsqrtf(ss * (1.f / 72.f) + 1e-6f);
    float x[72];
    #pragma unroll
    for (int i = 0; i < 9; i++)
      #pragma unroll
      for (int e = 0; e < 8; e++){ int d = i * 8 + e; x[d] = bf2f(xr[i][e]) * rs_ * sc[d]; }
    #pragma unroll
    for (int c = 0; c < 2; c++)
      #pragma unroll
      for (int j = 0; j < 18; j++){
        float co = tc[(size_t)tok * 36 + c * 18 + j];
        float si = ts[(size_t)tok * 36 + c * 18 + j];
        float x1 = x[c * 36 + j], x2 = x[c * 36 + j + 18];
        x[c * 36 + j]      = x1 * co - x2 * si;   // rotate_half within 36-block
        x[c * 36 + j + 18] = x2 * co + x1 * si;
      }
    size_t off = ((size_t)bh * 1024 + n) * DPAD;
    #pragma unroll
    for (int i = 0; i < 9; i++){
      u16x8 o;
      #pragma unroll
      for (int e = 0; e < 8; e++) o[e] = f2bf(x[i * 8 + e] * fold);
      *(u16x8*)(dst + off + i * 8) = o;
    }
    u16x8 z = {0,0,0,0,0,0,0,0};
    #pragma unroll
    for (int i = 9; i < 12; i++) *(u16x8*)(dst + off + i * 8) = z;  // zero pad 72..95
  }
  __syncthreads();
  // ---- V transpose out: Vt[bh][d][n], row 72 = ones, 73..79 zeroed ----
  u16x8 z = {0,0,0,0,0,0,0,0};
  u16x8 on = {0x3F80,0x3F80,0x3F80,0x3F80,0x3F80,0x3F80,0x3F80,0x3F80};
  for (int c = tid; c < VROWS * 32; c += 256){
    int row = c >> 5, seg = c & 31;
    u16x8 v;
    if (row < 72)       v = *(const u16x8*)&vl[row][seg * 8];
    else if (row == 72) v = on;
    else                v = z;
    *(u16x8*)(Vt + ((size_t)bh * VROWS + row) * 1024 + n0 + seg * 8) = v;
  }
}

// ------------- flash attention, 8 waves x 32 q, no-max softmax ---------
// S (from MFMA) is already log2-domain (Q pre-scaled). |S| <= 12.25 by
// Cauchy-Schwarz (rms-normed q,k) => exp2 never overflows: no running max,
// no rescale. Denominator = accO col 72 (V ones row).
__global__ __launch_bounds__(512, 4) void attn(const u16* __restrict__ Qp, const u16* __restrict__ Kp,
                                               const u16* __restrict__ Vt, u16* __restrict__ AO){
  __shared__ u16 Kl[64][104];        // 208B stride
  __shared__ u16 Vl[VROWS][72];      // 144B stride
  __shared__ u16 Pl[8][32][72];      // per-wave P, 144B stride
  int tid = threadIdx.x, lane = tid & 63, w = tid >> 6;
  int l16 = lane & 15, lq = lane >> 4;
  int bh = blockIdx.y, b = bh >> 4, h = bh & 15;
  int q0 = blockIdx.x * 256;
  const u16* Qb = Qp + (size_t)bh * 1024 * DPAD;
  const u16* Kb = Kp + (size_t)bh * 1024 * DPAD;
  const u16* Vb = Vt + (size_t)bh * VROWS * 1024;

  bf16x8 qf[2][3];
  #pragma unroll
  for (int mt = 0; mt < 2; mt++)
    #pragma unroll
    for (int ks = 0; ks < 3; ks++)
      qf[mt][ks] = *(const bf16x8*)(Qb + (size_t)(q0 + w * 32 + mt * 16 + l16) * DPAD + ks * 32 + lq * 8);

  f32x4 accO[2][5] = {};

  for (int kv = 0; kv < 16; ++kv){
    __syncthreads();
    for (int c = tid; c < 768; c += 512){          // K tile 64x96
      int row = c / 12, col = c - row * 12;
      *(u16x8*)&Kl[row][col * 8] = *(const u16x8*)(Kb + (size_t)(kv * 64 + row) * DPAD + col * 8);
    }
    for (int c = tid; c < VROWS * 8; c += 512){    // V^T tile 80x64
      int row = c >> 3, seg = c & 7;
      *(u16x8*)&Vl[row][seg * 8] = *(const u16x8*)(Vb + (size_t)row * 1024 + kv * 64 + seg * 8);
    }
    __syncthreads();

    f32x4 accS[2][4] = {};
    #pragma unroll
    for (int j = 0; j < 4; j++)
      #pragma unroll
      for (int ks = 0; ks < 3; ks++){
        bf16x8 kf = *(const bf16x8*)&Kl[j * 16 + l16][ks * 32 + lq * 8];
        accS[0][j] = __builtin_amdgcn_mfma_f32_16x16x32_bf16(qf[0][ks], kf, accS[0][j], 0, 0, 0);
        accS[1][j] = __builtin_amdgcn_mfma_f32_16x16x32_bf16(qf[1][ks], kf, accS[1][j], 0, 0, 0);
      }
    #pragma unroll
    for (int mt = 0; mt < 2; mt++)
      #pragma unroll
      for (int j = 0; j < 4; j++)
        #pragma unroll
        for (int r = 0; r < 4; r++)
          Pl[w][mt * 16 + lq * 4 + r][j * 16 + l16] = f2bf(exp2f(accS[mt][j][r]));
    #pragma unroll
    for (int ks = 0; ks < 2; ks++){
      bf16x8 pf0 = *(const bf16x8*)&Pl[w][l16][ks * 32 + lq * 8];
      bf16x8 pf1 = *(const bf16x8*)&Pl[w][16 + l16][ks * 32 + lq * 8];
      #pragma unroll
      for (int nf = 0; nf < 5; nf++){
        bf16x8 vf = *(const bf16x8*)&Vl[nf * 16 + l16][ks * 32 + lq * 8];
        accO[0][nf] = __builtin_amdgcn_mfma_f32_16x16x32_bf16(pf0, vf, accO[0][nf], 0, 0, 0);
        accO[1][nf] = __builtin_amdgcn_mfma_f32_16x16x32_bf16(pf1, vf, accO[1][nf], 0, 0, 0);
      }
    }
  }
  #pragma unroll
  for (int mt = 0; mt < 2; mt++)
    #pragma unroll
    for (int r = 0; r < 4; r++){
      float s = __shfl(accO[mt][4][r], (lane & 48) + 8);   // col 72 = denominator
      float inv = 1.f / s;
      int qg = q0 + w * 32 + mt * 16 + lq * 4 + r;
      size_t rowoff = ((size_t)(b * 1024 + qg)) * DMODEL + h * DHEAD;
      #pragma unroll
      for (int nf = 0; nf < 5; nf++){
        int d = nf * 16 + l16;
        if (d < 72) AO[rowoff + d] = f2bf(accO[mt][nf][r] * inv);
      }
    }
}

extern "C" void kernel_launch(void* const* d_in, const int* in_sizes, int n_in,
                              void* d_out, int out_size, void* d_ws, size_t ws_size,
                              hipStream_t stream){
  const float* X   = (const float*)d_in[0];
  const int*   pid = (const int*)  d_in[1];
  const float* Wq  = (const float*)d_in[2];
  const float* Wk  = (const float*)d_in[3];
  const float* Wv  = (const float*)d_in[4];
  const float* Wo  = (const float*)d_in[5];
  const float* qsc = (const float*)d_in[6];
  const float* ksc = (const float*)d_in[7];
  const float* vsc = (const float*)d_in[8];
  char* ws = (char*)d_ws;
  u16*   Xb  = (u16*)(ws);                    // 18,874,368
  u16*   WT  = (u16*)(ws + 18874368);         // 10,616,832
  u16*   QKV = (u16*)(ws + 29491200);         // 56,623,104
  u16*   Qp  = (u16*)(ws + 86114304);         // 25,165,824
  u16*   Kp  = (u16*)(ws + 111280128);        // 25,165,824
  u16*   Vt  = (u16*)(ws + 136445952);        // 20,971,520
  float* tc  = (float*)(ws + 157417472);      // 1,179,648
  float* tsn = (float*)(ws + 158597120);      // 1,179,648
  u16*   AO  = QKV;                           // alias: QKV dead after rmsrope

  cvt_x  <<<4608, 256, 0, stream>>>(X, Xb);
  pack_w <<<dim3(36, 144), 256, 0, stream>>>(Wq, Wk, Wv, Wo, WT);
  rope_tab<<<1152, 256, 0, stream>>>(pid, tc, tsn);
  gemm_bt<0><<<dim3(64, 27), 256, 0, stream>>>(Xb, WT, QKV, 3456);
  rmsrope<<<dim3(32, 16), 256, 0, stream>>>(QKV, tc, tsn, qsc, ksc, vsc, Qp, Kp, Vt);
  attn   <<<dim3(4, 128), 512, 0, stream>>>(Qp, Kp, Vt, AO);
  gemm_bt<1><<<dim3(64, 9), 256, 0, stream>>>(AO, WT + (size_t)3456 * 1152, d_out, 1152);
}

// Round 7
// 358.035 us; speedup vs baseline: 1.2157x; 1.0473x over previous
//
#include <hip/hip_runtime.h>
#include <hip/hip_bf16.h>

typedef unsigned short u16;
typedef __attribute__((ext_vector_type(8))) short bf16x8;
typedef __attribute__((ext_vector_type(8))) unsigned short u16x8;
typedef __attribute__((ext_vector_type(4))) float f32x4;

#define NTOK 8192
#define DMODEL 1152
#define NHEAD 16
#define DHEAD 72
#define DPAD 96
#define VROWS 80
#define NQKV 3456

__device__ __forceinline__ u16 f2bf(float f){
  __hip_bfloat16 h = __float2bfloat16(f);
  return *reinterpret_cast<u16*>(&h);
}
__device__ __forceinline__ float bf2f(u16 u){
  union { unsigned int i; float f; } v; v.i = ((unsigned int)u) << 16; return v.f;
}
__device__ __forceinline__ void gload16(const void* g, void* l){
  __builtin_amdgcn_global_load_lds((const __attribute__((address_space(1))) void*)g,
                                   (__attribute__((address_space(3))) void*)l, 16, 0, 0);
}

#define FENCE asm volatile("" ::: "memory")
#define BARX() do{ FENCE; __builtin_amdgcn_s_barrier(); FENCE; }while(0)
#define LGK0 asm volatile("s_waitcnt lgkmcnt(0)" ::: "memory")
#define VMW(N) asm volatile("s_waitcnt vmcnt(" #N ")" ::: "memory")
#define PRIO1 __builtin_amdgcn_s_setprio(1)
#define PRIO0 __builtin_amdgcn_s_setprio(0)

// ---------------- fp32 -> bf16 convert of hidden_states ----------------
__global__ __launch_bounds__(256) void cvt_x(const float* __restrict__ X, u16* __restrict__ Xb){
  int i = (blockIdx.x * 256 + threadIdx.x) * 8;
  float4 a = *(const float4*)(X + i);
  float4 b = *(const float4*)(X + i + 4);
  u16x8 o;
  o[0]=f2bf(a.x); o[1]=f2bf(a.y); o[2]=f2bf(a.z); o[3]=f2bf(a.w);
  o[4]=f2bf(b.x); o[5]=f2bf(b.y); o[6]=f2bf(b.z); o[7]=f2bf(b.w);
  *(u16x8*)(Xb + i) = o;
}

// ------------- transpose+convert weights: WT[n][k] = W[k][n] -----------
__global__ __launch_bounds__(256) void pack_w(const float* __restrict__ Wq, const float* __restrict__ Wk,
                                              const float* __restrict__ Wv, const float* __restrict__ Wo,
                                              u16* __restrict__ WT){
  __shared__ u16 t[32][33];
  int tx = threadIdx.x & 31, ty = threadIdx.x >> 5;
  int k0 = blockIdx.x * 32, n0 = blockIdx.y * 32;
  int ng = n0 + tx;
  const float* W; int nl;
  if (ng < 1152)      { W = Wq; nl = ng; }
  else if (ng < 2304) { W = Wk; nl = ng - 1152; }
  else if (ng < 3456) { W = Wv; nl = ng - 2304; }
  else                { W = Wo; nl = ng - 3456; }
  #pragma unroll
  for (int i = 0; i < 4; i++)
    t[ty + i*8][tx] = f2bf(W[(size_t)(k0 + ty + i*8) * 1152 + nl]);
  __syncthreads();
  #pragma unroll
  for (int i = 0; i < 4; i++)
    WT[(size_t)(n0 + ty + i*8) * 1152 + k0 + tx] = t[tx][ty + i*8];
}

// ---------------- RoPE cos/sin table: [token][c*18+j] ------------------
__global__ __launch_bounds__(256) void rope_tab(const int* __restrict__ pid,
                                                float* __restrict__ tc, float* __restrict__ ts){
  int i = blockIdx.x * 256 + threadIdx.x;
  if (i >= NTOK * 36) return;
  int tok = i / 36, r = i - tok * 36;
  int c = r / 18, j = r - c * 18;
  float freq = exp2f(-0.7382062433f * (float)j);   // 10000^(-2j/36)
  float ang = (float)pid[tok * 2 + c] * freq;
  float s, co;
  sincosf(ang, &s, &co);
  tc[i] = co; ts[i] = s;
}

// ===================== 256x256 8-phase GEMM (QKV) ======================
// C[8192][3456](bf16) = A[8192][1152] * Bt[n][1152]^T, n-tiles padded to 3584
// (pad B-rows read Wo data: finite; pad C-cols never stored).
// T2 swizzle: LDS byte ^= (row&7)<<4 (read) + inverse-swizzled global src.
// T3/T4: 8 phases, 1 half-tile staged/phase, vmcnt(4) at P4/P8 (never 0
// except tail). T5: setprio around each 16-MFMA quadrant.
#define REG(b,idx) ((b)*32768 + (idx)*8192)   // u16 offset; idx: 0=A0,1=A1,2=B0,3=B1

__device__ __forceinline__ void stage_half(const char* g, u16* lreg, int w, int lane){
  #pragma unroll
  for (int j = 0; j < 2; j++){
    int row = j*64 + w*8 + (lane >> 3);
    int chunk = (lane & 7) ^ (row & 7);
    gload16(g + (size_t)row*2304 + chunk*16, (char*)lreg + j*8192 + w*1024);
  }
}
__device__ __forceinline__ void rdA(bf16x8 (&d)[4][2], const u16* L, int b, int wm, int mbase, int l16, int lq){
  #pragma unroll
  for (int mi = 0; mi < 4; mi++)
    #pragma unroll
    for (int kk = 0; kk < 2; kk++){
      int rl = (mbase + mi)*16 + l16;
      int byt = (rl*128 + kk*64 + lq*16) ^ ((rl & 7) << 4);
      d[mi][kk] = *(const bf16x8*)((const char*)L + (size_t)REG(b, wm)*2 + byt);
    }
}
__device__ __forceinline__ void rdB(bf16x8 (&d)[2][2], const u16* L, int b, int wn, int nbase, int l16, int lq){
  #pragma unroll
  for (int ni = 0; ni < 2; ni++)
    #pragma unroll
    for (int kk = 0; kk < 2; kk++){
      int rl = (wn & 1)*64 + (nbase + ni)*16 + l16;
      int byt = (rl*128 + kk*64 + lq*16) ^ ((rl & 7) << 4);
      d[ni][kk] = *(const bf16x8*)((const char*)L + (size_t)REG(b, 2 + (wn >> 1))*2 + byt);
    }
}
template<int MB, int NB>
__device__ __forceinline__ void quad(f32x4 (&acc)[8][4], const bf16x8 (&aa)[4][2], const bf16x8 (&bb)[2][2]){
  #pragma unroll
  for (int mi = 0; mi < 4; mi++)
    #pragma unroll
    for (int ni = 0; ni < 2; ni++)
      #pragma unroll
      for (int kk = 0; kk < 2; kk++)
        acc[MB+mi][NB+ni] = __builtin_amdgcn_mfma_f32_16x16x32_bf16(aa[mi][kk], bb[ni][kk], acc[MB+mi][NB+ni], 0, 0, 0);
}

__global__ __launch_bounds__(512, 2) void gemm256(const u16* __restrict__ A, const u16* __restrict__ Bt,
                                                  u16* __restrict__ C){
  __shared__ u16 L[65536];                      // 128 KiB: 2 bufs x (A0,A1,B0,B1) halves
  int tid = threadIdx.x, lane = tid & 63, w = tid >> 6;
  int wm = w >> 2, wn = w & 3;
  int l16 = lane & 15, lq = lane >> 4;
  int bid = blockIdx.x;
  int swz = (bid & 7) * 56 + (bid >> 3);        // XCD swizzle (448 % 8 == 0)
  int m0 = (swz & 31) * 256, n0 = (swz >> 5) * 256;
  const char* Ab = (const char*)A  + (size_t)m0 * 2304;
  const char* Bb = (const char*)Bt + (size_t)n0 * 2304;
  f32x4 acc[8][4] = {};
  bf16x8 a[4][2], a2[4][2], b0[2][2], b1[2][2];

  // prologue: buf0 <- kt0 (A0,A1,B0,B1), buf1 <- kt1 (B0,B1)
  stage_half(Ab,                          L + REG(0,0), w, lane);
  stage_half(Ab + (size_t)128*2304,       L + REG(0,1), w, lane);
  stage_half(Bb,                          L + REG(0,2), w, lane);
  stage_half(Bb + (size_t)128*2304,       L + REG(0,3), w, lane);
  stage_half(Bb + 128,                    L + REG(1,2), w, lane);
  stage_half(Bb + (size_t)128*2304 + 128, L + REG(1,3), w, lane);
  VMW(4); BARX();

  #pragma unroll 1
  for (int i = 0; i < 9; ++i){
    bool pf = (i < 8);
    size_t k1 = (size_t)(2*i+1)*128, k2 = (size_t)(2*i+2)*128, k3 = (size_t)(2*i+3)*128;
    // ---- P1: Q0 of buf0 (kt 2i)
    rdA(a,  L, 0, wm, 0, l16, lq);
    rdB(b0, L, 0, wn, 0, l16, lq);
    stage_half(Ab + k1, L + REG(1,0), w, lane);                       // buf1.A0 <- kt 2i+1
    BARX(); LGK0; PRIO1; quad<0,0>(acc, a, b0); PRIO0; BARX();
    // ---- P2: Q1
    rdB(b1, L, 0, wn, 2, l16, lq);
    stage_half(Ab + (size_t)128*2304 + k1, L + REG(1,1), w, lane);    // buf1.A1 <- kt 2i+1
    BARX(); LGK0; PRIO1; quad<0,2>(acc, a, b1); PRIO0; BARX();
    // ---- P3: Q2
    rdA(a2, L, 0, wm, 4, l16, lq);
    if (pf) stage_half(Bb + k2, L + REG(0,2), w, lane);               // buf0.B0 <- kt 2i+2
    BARX(); LGK0; PRIO1; quad<4,0>(acc, a2, b0); PRIO0; BARX();
    // ---- P4: Q3
    if (pf) stage_half(Bb + (size_t)128*2304 + k2, L + REG(0,3), w, lane);
    BARX(); PRIO1; quad<4,2>(acc, a2, b1); PRIO0;
    if (pf) { VMW(4); } else { VMW(0); }
    BARX();
    // ---- P5: Q0 of buf1 (kt 2i+1)
    rdA(a,  L, 1, wm, 0, l16, lq);
    rdB(b0, L, 1, wn, 0, l16, lq);
    if (pf) stage_half(Ab + k2, L + REG(0,0), w, lane);               // buf0.A0 <- kt 2i+2
    BARX(); LGK0; PRIO1; quad<0,0>(acc, a, b0); PRIO0; BARX();
    // ---- P6: Q1
    rdB(b1, L, 1, wn, 2, l16, lq);
    if (pf) stage_half(Ab + (size_t)128*2304 + k2, L + REG(0,1), w, lane);
    BARX(); LGK0; PRIO1; quad<0,2>(acc, a, b1); PRIO0; BARX();
    // ---- P7: Q2
    rdA(a2, L, 1, wm, 4, l16, lq);
    if (pf) stage_half(Bb + k3, L + REG(1,2), w, lane);               // buf1.B0 <- kt 2i+3
    BARX(); LGK0; PRIO1; quad<4,0>(acc, a2, b0); PRIO0; BARX();
    // ---- P8: Q3
    if (pf) stage_half(Bb + (size_t)128*2304 + k3, L + REG(1,3), w, lane);
    BARX(); PRIO1; quad<4,2>(acc, a2, b1); PRIO0;
    if (pf) { VMW(4); } else { VMW(0); }
    BARX();
  }
  // epilogue: guarded store (pad cols 3456..3583 dropped)
  #pragma unroll
  for (int mi = 0; mi < 8; mi++)
    #pragma unroll
    for (int ni = 0; ni < 4; ni++)
      #pragma unroll
      for (int r = 0; r < 4; r++){
        int row = m0 + wm*128 + mi*16 + lq*4 + r;
        int col = n0 + wn*64 + ni*16 + l16;
        if (col < NQKV) C[(size_t)row * NQKV + col] = f2bf(acc[mi][ni][r]);
      }
}

// --------- GEMM: C[M][Ncols] = A[M][1152] * Bt[Ncols][1152]^T ----------
// m97-style 128x128 tile (used for the fp32-output Wo projection).
template<int FP32OUT>
__global__ __launch_bounds__(256) void gemm_bt(const u16* __restrict__ A, const u16* __restrict__ Bt,
                                               void* __restrict__ C, int Ncols){
  __shared__ u16 Al[128 * 64];
  __shared__ u16 Bl[128 * 64];
  int tid = threadIdx.x, lane = tid & 63, w = tid >> 6;
  int wr = w >> 1, wc = w & 1, l16 = lane & 15, lq = lane >> 4;
  int m0 = blockIdx.x * 128, n0 = blockIdx.y * 128;
  f32x4 acc[4][4] = {};
  int grow = lane >> 3;
  int gchunk = (lane & 7) ^ grow;                    // pre-swizzled global source
  const char* Abase = (const char*)A  + (size_t)(m0 + grow) * 2304 + gchunk * 16;
  const char* Bbase = (const char*)Bt + (size_t)(n0 + grow) * 2304 + gchunk * 16;
  int sw = l16 & 7;
  for (int kt = 0; kt < 18; ++kt){
    __syncthreads();
    #pragma unroll
    for (int i = 0; i < 4; i++){
      int j = w * 4 + i;
      gload16(Abase + (size_t)j * 8 * 2304 + kt * 128, &Al[j * 512]);
      gload16(Bbase + (size_t)j * 8 * 2304 + kt * 128, &Bl[j * 512]);
    }
    __syncthreads();
    #pragma unroll
    for (int kk = 0; kk < 2; kk++){
      bf16x8 af[4], bfr[4];
      #pragma unroll
      for (int m = 0; m < 4; m++){
        int row = wr * 64 + m * 16 + l16;
        af[m] = *(const bf16x8*)&Al[row * 64 + (((kk * 4 + lq) ^ sw) * 8)];
      }
      #pragma unroll
      for (int n = 0; n < 4; n++){
        int row = wc * 64 + n * 16 + l16;
        bfr[n] = *(const bf16x8*)&Bl[row * 64 + (((kk * 4 + lq) ^ sw) * 8)];
      }
      #pragma unroll
      for (int m = 0; m < 4; m++)
        #pragma unroll
        for (int n = 0; n < 4; n++)
          acc[m][n] = __builtin_amdgcn_mfma_f32_16x16x32_bf16(af[m], bfr[n], acc[m][n], 0, 0, 0);
    }
  }
  #pragma unroll
  for (int m = 0; m < 4; m++)
    #pragma unroll
    for (int n = 0; n < 4; n++)
      #pragma unroll
      for (int r = 0; r < 4; r++){
        int row = m0 + wr * 64 + m * 16 + lq * 4 + r;
        int col = n0 + wc * 64 + n * 16 + l16;
        if (FP32OUT) ((float*)C)[(size_t)row * Ncols + col] = acc[m][n][r];
        else         ((u16*)  C)[(size_t)row * Ncols + col] = f2bf(acc[m][n][r]);
      }
}

// ------------- RMS norm + RoPE + layouts for attention -----------------
__global__ __launch_bounds__(256) void rmsrope(const u16* __restrict__ QKV,
    const float* __restrict__ tc, const float* __restrict__ ts,
    const float* __restrict__ qsc, const float* __restrict__ ksc, const float* __restrict__ vsc,
    u16* __restrict__ Qp, u16* __restrict__ Kp, u16* __restrict__ Vt){
  __shared__ u16 vl[72][264];
  int h = blockIdx.y, tid = threadIdx.x;
  int tok = blockIdx.x * 256 + tid;
  int b = tok >> 10, n = tok & 1023;
  int n0 = (blockIdx.x & 3) * 256;
  int bh = b * NHEAD + h;
  const u16* base = QKV + (size_t)tok * NQKV + h * DHEAD;

  { // ---- V: RMS norm -> LDS (for transpose) ----
    u16x8 vr[9];
    #pragma unroll
    for (int i = 0; i < 9; i++) vr[i] = *(const u16x8*)(base + 2304 + i * 8);
    float ss = 0.f;
    #pragma unroll
    for (int i = 0; i < 9; i++)
      #pragma unroll
      for (int e = 0; e < 8; e++){ float f = bf2f(vr[i][e]); ss += f * f; }
    float rv = rsqrtf(ss * (1.f / 72.f) + 1e-6f);
    #pragma unroll
    for (int i = 0; i < 9; i++)
      #pragma unroll
      for (int e = 0; e < 8; e++){
        int d = i * 8 + e;
        vl[d][tid] = f2bf(bf2f(vr[i][e]) * rv * vsc[d]);
      }
  }
  // ---- Q then K: RMS norm + RoPE ----
  #pragma unroll
  for (int qk = 0; qk < 2; ++qk){
    const u16* src = base + qk * 1152;
    const float* sc = qk ? ksc : qsc;
    u16* dst = qk ? Kp : Qp;
    float fold = qk ? 1.0f : 0.17002219f;        // Q *= 72^-0.5 * log2(e)
    u16x8 xr[9];
    #pragma unroll
    for (int i = 0; i < 9; i++) xr[i] = *(const u16x8*)(src + i * 8);
    float ss = 0.f;
    #pragma unroll
    for (int i = 0; i < 9; i++)
      #pragma unroll
      for (int e = 0; e < 8; e++){ float f = bf2f(xr[i][e]); ss += f * f; }
    float rs_ = rsqrtf(ss * (1.f / 72.f) + 1e-6f);
    float x[72];
    #pragma unroll
    for (int i = 0; i < 9; i++)
      #pragma unroll
      for (int e = 0; e < 8; e++){ int d = i * 8 + e; x[d] = bf2f(xr[i][e]) * rs_ * sc[d]; }
    #pragma unroll
    for (int c = 0; c < 2; c++)
      #pragma unroll
      for (int j = 0; j < 18; j++){
        float co = tc[(size_t)tok * 36 + c * 18 + j];
        float si = ts[(size_t)tok * 36 + c * 18 + j];
        float x1 = x[c * 36 + j], x2 = x[c * 36 + j + 18];
        x[c * 36 + j]      = x1 * co - x2 * si;
        x[c * 36 + j + 18] = x2 * co + x1 * si;
      }
    size_t off = ((size_t)bh * 1024 + n) * DPAD;
    #pragma unroll
    for (int i = 0; i < 9; i++){
      u16x8 o;
      #pragma unroll
      for (int e = 0; e < 8; e++) o[e] = f2bf(x[i * 8 + e] * fold);
      *(u16x8*)(dst + off + i * 8) = o;
    }
    u16x8 z = {0,0,0,0,0,0,0,0};
    #pragma unroll
    for (int i = 9; i < 12; i++) *(u16x8*)(dst + off + i * 8) = z;
  }
  __syncthreads();
  // ---- V transpose out: Vt[bh][d][n], row 72 = ones, 73..79 zeroed ----
  u16x8 z = {0,0,0,0,0,0,0,0};
  u16x8 on = {0x3F80,0x3F80,0x3F80,0x3F80,0x3F80,0x3F80,0x3F80,0x3F80};
  for (int c = tid; c < VROWS * 32; c += 256){
    int row = c >> 5, seg = c & 31;
    u16x8 v;
    if (row < 72)       v = *(const u16x8*)&vl[row][seg * 8];
    else if (row == 72) v = on;
    else                v = z;
    *(u16x8*)(Vt + ((size_t)bh * VROWS + row) * 1024 + n0 + seg * 8) = v;
  }
}

// ------------- flash attention, 8 waves x 32 q, no-max softmax ---------
__global__ __launch_bounds__(512, 4) void attn(const u16* __restrict__ Qp, const u16* __restrict__ Kp,
                                               const u16* __restrict__ Vt, u16* __restrict__ AO){
  __shared__ u16 Kl[64][104];
  __shared__ u16 Vl[VROWS][72];
  __shared__ u16 Pl[8][32][72];
  int tid = threadIdx.x, lane = tid & 63, w = tid >> 6;
  int l16 = lane & 15, lq = lane >> 4;
  int bh = blockIdx.y, b = bh >> 4, h = bh & 15;
  int q0 = blockIdx.x * 256;
  const u16* Qb = Qp + (size_t)bh * 1024 * DPAD;
  const u16* Kb = Kp + (size_t)bh * 1024 * DPAD;
  const u16* Vb = Vt + (size_t)bh * VROWS * 1024;

  bf16x8 qf[2][3];
  #pragma unroll
  for (int mt = 0; mt < 2; mt++)
    #pragma unroll
    for (int ks = 0; ks < 3; ks++)
      qf[mt][ks] = *(const bf16x8*)(Qb + (size_t)(q0 + w * 32 + mt * 16 + l16) * DPAD + ks * 32 + lq * 8);

  f32x4 accO[2][5] = {};

  for (int kv = 0; kv < 16; ++kv){
    __syncthreads();
    for (int c = tid; c < 768; c += 512){
      int row = c / 12, col = c - row * 12;
      *(u16x8*)&Kl[row][col * 8] = *(const u16x8*)(Kb + (size_t)(kv * 64 + row) * DPAD + col * 8);
    }
    for (int c = tid; c < VROWS * 8; c += 512){
      int row = c >> 3, seg = c & 7;
      *(u16x8*)&Vl[row][seg * 8] = *(const u16x8*)(Vb + (size_t)row * 1024 + kv * 64 + seg * 8);
    }
    __syncthreads();

    f32x4 accS[2][4] = {};
    #pragma unroll
    for (int j = 0; j < 4; j++)
      #pragma unroll
      for (int ks = 0; ks < 3; ks++){
        bf16x8 kf = *(const bf16x8*)&Kl[j * 16 + l16][ks * 32 + lq * 8];
        accS[0][j] = __builtin_amdgcn_mfma_f32_16x16x32_bf16(qf[0][ks], kf, accS[0][j], 0, 0, 0);
        accS[1][j] = __builtin_amdgcn_mfma_f32_16x16x32_bf16(qf[1][ks], kf, accS[1][j], 0, 0, 0);
      }
    #pragma unroll
    for (int mt = 0; mt < 2; mt++)
      #pragma unroll
      for (int j = 0; j < 4; j++)
        #pragma unroll
        for (int r = 0; r < 4; r++)
          Pl[w][mt * 16 + lq * 4 + r][j * 16 + l16] = f2bf(exp2f(accS[mt][j][r]));
    #pragma unroll
    for (int ks = 0; ks < 2; ks++){
      bf16x8 pf0 = *(const bf16x8*)&Pl[w][l16][ks * 32 + lq * 8];
      bf16x8 pf1 = *(const bf16x8*)&Pl[w][16 + l16][ks * 32 + lq * 8];
      #pragma unroll
      for (int nf = 0; nf < 5; nf++){
        bf16x8 vf = *(const bf16x8*)&Vl[nf * 16 + l16][ks * 32 + lq * 8];
        accO[0][nf] = __builtin_amdgcn_mfma_f32_16x16x32_bf16(pf0, vf, accO[0][nf], 0, 0, 0);
        accO[1][nf] = __builtin_amdgcn_mfma_f32_16x16x32_bf16(pf1, vf, accO[1][nf], 0, 0, 0);
      }
    }
  }
  #pragma unroll
  for (int mt = 0; mt < 2; mt++)
    #pragma unroll
    for (int r = 0; r < 4; r++){
      float s = __shfl(accO[mt][4][r], (lane & 48) + 8);   // col 72 = denominator
      float inv = 1.f / s;
      int qg = q0 + w * 32 + mt * 16 + lq * 4 + r;
      size_t rowoff = ((size_t)(b * 1024 + qg)) * DMODEL + h * DHEAD;
      #pragma unroll
      for (int nf = 0; nf < 5; nf++){
        int d = nf * 16 + l16;
        if (d < 72) AO[rowoff + d] = f2bf(accO[mt][nf][r] * inv);
      }
    }
}

extern "C" void kernel_launch(void* const* d_in, const int* in_sizes, int n_in,
                              void* d_out, int out_size, void* d_ws, size_t ws_size,
                              hipStream_t stream){
  const float* X   = (const float*)d_in[0];
  const int*   pid = (const int*)  d_in[1];
  const float* Wq  = (const float*)d_in[2];
  const float* Wk  = (const float*)d_in[3];
  const float* Wv  = (const float*)d_in[4];
  const float* Wo  = (const float*)d_in[5];
  const float* qsc = (const float*)d_in[6];
  const float* ksc = (const float*)d_in[7];
  const float* vsc = (const float*)d_in[8];
  char* ws = (char*)d_ws;
  u16*   Xb  = (u16*)(ws);                    // 18,874,368
  u16*   WT  = (u16*)(ws + 18874368);         // 10,616,832
  u16*   QKV = (u16*)(ws + 29491200);         // 56,623,104
  u16*   Qp  = (u16*)(ws + 86114304);         // 25,165,824
  u16*   Kp  = (u16*)(ws + 111280128);        // 25,165,824
  u16*   Vt  = (u16*)(ws + 136445952);        // 20,971,520
  float* tc  = (float*)(ws + 157417472);      // 1,179,648
  float* tsn = (float*)(ws + 158597120);      // 1,179,648
  u16*   AO  = QKV;                           // alias: QKV dead after rmsrope

  cvt_x  <<<4608, 256, 0, stream>>>(X, Xb);
  pack_w <<<dim3(36, 144), 256, 0, stream>>>(Wq, Wk, Wv, Wo, WT);
  rope_tab<<<1152, 256, 0, stream>>>(pid, tc, tsn);
  gemm256<<<448, 512, 0, stream>>>(Xb, WT, QKV);
  rmsrope<<<dim3(32, 16), 256, 0, stream>>>(QKV, tc, tsn, qsc, ksc, vsc, Qp, Kp, Vt);
  attn   <<<dim3(4, 128), 512, 0, stream>>>(Qp, Kp, Vt, AO);
  gemm_bt<1><<<dim3(64, 9), 256, 0, stream>>>(AO, WT + (size_t)3456 * 1152, d_out, 1152);
}

// Round 11
// 351.956 us; speedup vs baseline: 1.2367x; 1.0173x over previous
//
#include <hip/hip_runtime.h>
#include <hip/hip_bf16.h>

typedef unsigned short u16;
typedef __attribute__((ext_vector_type(8))) short bf16x8;
typedef __attribute__((ext_vector_type(8))) unsigned short u16x8;
typedef __attribute__((ext_vector_type(4))) float f32x4;

#define NTOK 8192
#define DMODEL 1152
#define NHEAD 16
#define DHEAD 72
#define DPAD 96
#define VROWS 80
#define NQKV 3456

__device__ __forceinline__ u16 f2bf(float f){
  __hip_bfloat16 h = __float2bfloat16(f);
  return *reinterpret_cast<u16*>(&h);
}
__device__ __forceinline__ float bf2f(u16 u){
  union { unsigned int i; float f; } v; v.i = ((unsigned int)u) << 16; return v.f;
}
__device__ __forceinline__ void gload16(const void* g, void* l){
  __builtin_amdgcn_global_load_lds((const __attribute__((address_space(1))) void*)g,
                                   (__attribute__((address_space(3))) void*)l, 16, 0, 0);
}

#define FENCE asm volatile("" ::: "memory")
#define BARX() do{ FENCE; __builtin_amdgcn_s_barrier(); FENCE; }while(0)
#define LGK0 asm volatile("s_waitcnt lgkmcnt(0)" ::: "memory")
#define VMW(N) asm volatile("s_waitcnt vmcnt(" #N ")" ::: "memory")
#define PRIO1 __builtin_amdgcn_s_setprio(1)
#define PRIO0 __builtin_amdgcn_s_setprio(0)

// ---- fused prep: cvt_x (blocks 0..4607) | pack_w (4608..9791) | rope_tab ----
__global__ __launch_bounds__(256) void prep(const float* __restrict__ X, u16* __restrict__ Xb,
    const float* __restrict__ Wq, const float* __restrict__ Wk,
    const float* __restrict__ Wv, const float* __restrict__ Wo, u16* __restrict__ WT,
    const int* __restrict__ pid, float* __restrict__ tc, float* __restrict__ ts){
  __shared__ u16 t[32][33];
  int bid = blockIdx.x, tid = threadIdx.x;
  if (bid < 4608){
    int i = (bid * 256 + tid) * 8;
    float4 a = *(const float4*)(X + i);
    float4 b = *(const float4*)(X + i + 4);
    u16x8 o;
    o[0]=f2bf(a.x); o[1]=f2bf(a.y); o[2]=f2bf(a.z); o[3]=f2bf(a.w);
    o[4]=f2bf(b.x); o[5]=f2bf(b.y); o[6]=f2bf(b.z); o[7]=f2bf(b.w);
    *(u16x8*)(Xb + i) = o;
  } else if (bid < 9792){
    int p = bid - 4608;
    int tx = tid & 31, ty = tid >> 5;
    int k0 = (p % 36) * 32, n0 = (p / 36) * 32;
    int ng = n0 + tx;
    const float* W; int nl;
    if (ng < 1152)      { W = Wq; nl = ng; }
    else if (ng < 2304) { W = Wk; nl = ng - 1152; }
    else if (ng < 3456) { W = Wv; nl = ng - 2304; }
    else                { W = Wo; nl = ng - 3456; }
    #pragma unroll
    for (int i = 0; i < 4; i++)
      t[ty + i*8][tx] = f2bf(W[(size_t)(k0 + ty + i*8) * 1152 + nl]);
    __syncthreads();
    #pragma unroll
    for (int i = 0; i < 4; i++)
      WT[(size_t)(n0 + ty + i*8) * 1152 + k0 + tx] = t[tx][ty + i*8];
  } else {
    int i = (bid - 9792) * 256 + tid;
    if (i < NTOK * 36){
      int tok = i / 36, r = i - tok * 36;
      int c = r / 18, j = r - c * 18;
      float freq = exp2f(-0.7382062433f * (float)j);   // 10000^(-2j/36)
      float ang = (float)pid[tok * 2 + c] * freq;
      float s, co;
      sincosf(ang, &s, &co);
      tc[i] = co; ts[i] = s;
    }
  }
}

// ===================== 256x256 8-phase GEMM (QKV) ======================
#define REG(b,idx) ((b)*32768 + (idx)*8192)   // u16 offset; idx: 0=A0,1=A1,2=B0,3=B1

__device__ __forceinline__ void stage_half(const char* g, u16* lreg, int w, int lane){
  #pragma unroll
  for (int j = 0; j < 2; j++){
    int row = j*64 + w*8 + (lane >> 3);
    int chunk = (lane & 7) ^ (row & 7);
    gload16(g + (size_t)row*2304 + chunk*16, (char*)lreg + j*8192 + w*1024);
  }
}
__device__ __forceinline__ void rdA(bf16x8 (&d)[4][2], const u16* L, int b, int wm, int mbase, int l16, int lq){
  #pragma unroll
  for (int mi = 0; mi < 4; mi++)
    #pragma unroll
    for (int kk = 0; kk < 2; kk++){
      int rl = (mbase + mi)*16 + l16;
      int byt = (rl*128 + kk*64 + lq*16) ^ ((rl & 7) << 4);
      d[mi][kk] = *(const bf16x8*)((const char*)L + (size_t)REG(b, wm)*2 + byt);
    }
}
__device__ __forceinline__ void rdB(bf16x8 (&d)[2][2], const u16* L, int b, int wn, int nbase, int l16, int lq){
  #pragma unroll
  for (int ni = 0; ni < 2; ni++)
    #pragma unroll
    for (int kk = 0; kk < 2; kk++){
      int rl = (wn & 1)*64 + (nbase + ni)*16 + l16;
      int byt = (rl*128 + kk*64 + lq*16) ^ ((rl & 7) << 4);
      d[ni][kk] = *(const bf16x8*)((const char*)L + (size_t)REG(b, 2 + (wn >> 1))*2 + byt);
    }
}
template<int MB, int NB>
__device__ __forceinline__ void quad(f32x4 (&acc)[8][4], const bf16x8 (&aa)[4][2], const bf16x8 (&bb)[2][2]){
  #pragma unroll
  for (int mi = 0; mi < 4; mi++)
    #pragma unroll
    for (int ni = 0; ni < 2; ni++)
      #pragma unroll
      for (int kk = 0; kk < 2; kk++)
        acc[MB+mi][NB+ni] = __builtin_amdgcn_mfma_f32_16x16x32_bf16(aa[mi][kk], bb[ni][kk], acc[MB+mi][NB+ni], 0, 0, 0);
}

__global__ __launch_bounds__(512, 2) void gemm256(const u16* __restrict__ A, const u16* __restrict__ Bt,
                                                  u16* __restrict__ C){
  __shared__ u16 L[65536];                      // 128 KiB
  int tid = threadIdx.x, lane = tid & 63, w = tid >> 6;
  int wm = w >> 2, wn = w & 3;
  int l16 = lane & 15, lq = lane >> 4;
  int bid = blockIdx.x;
  int swz = (bid & 7) * 56 + (bid >> 3);        // XCD swizzle (448 % 8 == 0)
  int m0 = (swz & 31) * 256, n0 = (swz >> 5) * 256;
  const char* Ab = (const char*)A  + (size_t)m0 * 2304;
  const char* Bb = (const char*)Bt + (size_t)n0 * 2304;
  f32x4 acc[8][4] = {};
  bf16x8 a[4][2], a2[4][2], b0[2][2], b1[2][2];

  stage_half(Ab,                          L + REG(0,0), w, lane);
  stage_half(Ab + (size_t)128*2304,       L + REG(0,1), w, lane);
  stage_half(Bb,                          L + REG(0,2), w, lane);
  stage_half(Bb + (size_t)128*2304,       L + REG(0,3), w, lane);
  stage_half(Bb + 128,                    L + REG(1,2), w, lane);
  stage_half(Bb + (size_t)128*2304 + 128, L + REG(1,3), w, lane);
  VMW(4); BARX();

  #pragma unroll 1
  for (int i = 0; i < 9; ++i){
    bool pf = (i < 8);
    size_t k1 = (size_t)(2*i+1)*128, k2 = (size_t)(2*i+2)*128, k3 = (size_t)(2*i+3)*128;
    rdA(a,  L, 0, wm, 0, l16, lq);
    rdB(b0, L, 0, wn, 0, l16, lq);
    stage_half(Ab + k1, L + REG(1,0), w, lane);
    BARX(); LGK0; PRIO1; quad<0,0>(acc, a, b0); PRIO0; BARX();
    rdB(b1, L, 0, wn, 2, l16, lq);
    stage_half(Ab + (size_t)128*2304 + k1, L + REG(1,1), w, lane);
    BARX(); LGK0; PRIO1; quad<0,2>(acc, a, b1); PRIO0; BARX();
    rdA(a2, L, 0, wm, 4, l16, lq);
    if (pf) stage_half(Bb + k2, L + REG(0,2), w, lane);
    BARX(); LGK0; PRIO1; quad<4,0>(acc, a2, b0); PRIO0; BARX();
    if (pf) stage_half(Bb + (size_t)128*2304 + k2, L + REG(0,3), w, lane);
    BARX(); PRIO1; quad<4,2>(acc, a2, b1); PRIO0;
    if (pf) { VMW(4); } else { VMW(0); }
    BARX();
    rdA(a,  L, 1, wm, 0, l16, lq);
    rdB(b0, L, 1, wn, 0, l16, lq);
    if (pf) stage_half(Ab + k2, L + REG(0,0), w, lane);
    BARX(); LGK0; PRIO1; quad<0,0>(acc, a, b0); PRIO0; BARX();
    rdB(b1, L, 1, wn, 2, l16, lq);
    if (pf) stage_half(Ab + (size_t)128*2304 + k2, L + REG(0,1), w, lane);
    BARX(); LGK0; PRIO1; quad<0,2>(acc, a, b1); PRIO0; BARX();
    rdA(a2, L, 1, wm, 4, l16, lq);
    if (pf) stage_half(Bb + k3, L + REG(1,2), w, lane);
    BARX(); LGK0; PRIO1; quad<4,0>(acc, a2, b0); PRIO0; BARX();
    if (pf) stage_half(Bb + (size_t)128*2304 + k3, L + REG(1,3), w, lane);
    BARX(); PRIO1; quad<4,2>(acc, a2, b1); PRIO0;
    if (pf) { VMW(4); } else { VMW(0); }
    BARX();
  }
  #pragma unroll
  for (int mi = 0; mi < 8; mi++)
    #pragma unroll
    for (int ni = 0; ni < 4; ni++)
      #pragma unroll
      for (int r = 0; r < 4; r++){
        int row = m0 + wm*128 + mi*16 + lq*4 + r;
        int col = n0 + wn*64 + ni*16 + l16;
        if (col < NQKV) C[(size_t)row * NQKV + col] = f2bf(acc[mi][ni][r]);
      }
}

// --------- GEMM: C[M][Ncols] = A[M][1152] * Bt[Ncols][1152]^T ----------
template<int FP32OUT>
__global__ __launch_bounds__(256) void gemm_bt(const u16* __restrict__ A, const u16* __restrict__ Bt,
                                               void* __restrict__ C, int Ncols){
  __shared__ u16 Al[128 * 64];
  __shared__ u16 Bl[128 * 64];
  int tid = threadIdx.x, lane = tid & 63, w = tid >> 6;
  int wr = w >> 1, wc = w & 1, l16 = lane & 15, lq = lane >> 4;
  int m0 = blockIdx.x * 128, n0 = blockIdx.y * 128;
  f32x4 acc[4][4] = {};
  int grow = lane >> 3;
  int gchunk = (lane & 7) ^ grow;
  const char* Abase = (const char*)A  + (size_t)(m0 + grow) * 2304 + gchunk * 16;
  const char* Bbase = (const char*)Bt + (size_t)(n0 + grow) * 2304 + gchunk * 16;
  int sw = l16 & 7;
  for (int kt = 0; kt < 18; ++kt){
    __syncthreads();
    #pragma unroll
    for (int i = 0; i < 4; i++){
      int j = w * 4 + i;
      gload16(Abase + (size_t)j * 8 * 2304 + kt * 128, &Al[j * 512]);
      gload16(Bbase + (size_t)j * 8 * 2304 + kt * 128, &Bl[j * 512]);
    }
    __syncthreads();
    #pragma unroll
    for (int kk = 0; kk < 2; kk++){
      bf16x8 af[4], bfr[4];
      #pragma unroll
      for (int m = 0; m < 4; m++){
        int row = wr * 64 + m * 16 + l16;
        af[m] = *(const bf16x8*)&Al[row * 64 + (((kk * 4 + lq) ^ sw) * 8)];
      }
      #pragma unroll
      for (int n = 0; n < 4; n++){
        int row = wc * 64 + n * 16 + l16;
        bfr[n] = *(const bf16x8*)&Bl[row * 64 + (((kk * 4 + lq) ^ sw) * 8)];
      }
      #pragma unroll
      for (int m = 0; m < 4; m++)
        #pragma unroll
        for (int n = 0; n < 4; n++)
          acc[m][n] = __builtin_amdgcn_mfma_f32_16x16x32_bf16(af[m], bfr[n], acc[m][n], 0, 0, 0);
    }
  }
  #pragma unroll
  for (int m = 0; m < 4; m++)
    #pragma unroll
    for (int n = 0; n < 4; n++)
      #pragma unroll
      for (int r = 0; r < 4; r++){
        int row = m0 + wr * 64 + m * 16 + lq * 4 + r;
        int col = n0 + wc * 64 + n * 16 + l16;
        if (FP32OUT) ((float*)C)[(size_t)row * Ncols + col] = acc[m][n][r];
        else         ((u16*)  C)[(size_t)row * Ncols + col] = f2bf(acc[m][n][r]);
      }
}

// ------------- RMS norm + RoPE + layouts for attention -----------------
__global__ __launch_bounds__(256) void rmsrope(const u16* __restrict__ QKV,
    const float* __restrict__ tc, const float* __restrict__ ts,
    const float* __restrict__ qsc, const float* __restrict__ ksc, const float* __restrict__ vsc,
    u16* __restrict__ Qp, u16* __restrict__ Kp, u16* __restrict__ Vt){
  __shared__ u16 vl[72][264];
  int h = blockIdx.y, tid = threadIdx.x;
  int tok = blockIdx.x * 256 + tid;
  int b = tok >> 10, n = tok & 1023;
  int n0 = (blockIdx.x & 3) * 256;
  int bh = b * NHEAD + h;
  const u16* base = QKV + (size_t)tok * NQKV + h * DHEAD;

  {
    u16x8 vr[9];
    #pragma unroll
    for (int i = 0; i < 9; i++) vr[i] = *(const u16x8*)(base + 2304 + i * 8);
    float ss = 0.f;
    #pragma unroll
    for (int i = 0; i < 9; i++)
      #pragma unroll
      for (int e = 0; e < 8; e++){ float f = bf2f(vr[i][e]); ss += f * f; }
    float rv = rsqrtf(ss * (1.f / 72.f) + 1e-6f);
    #pragma unroll
    for (int i = 0; i < 9; i++)
      #pragma unroll
      for (int e = 0; e < 8; e++){
        int d = i * 8 + e;
        vl[d][tid] = f2bf(bf2f(vr[i][e]) * rv * vsc[d]);
      }
  }
  #pragma unroll
  for (int qk = 0; qk < 2; ++qk){
    const u16* src = base + qk * 1152;
    const float* sc = qk ? ksc : qsc;
    u16* dst = qk ? Kp : Qp;
    float fold = qk ? 1.0f : 0.17002219f;        // Q *= 72^-0.5 * log2(e)
    u16x8 xr[9];
    #pragma unroll
    for (int i = 0; i < 9; i++) xr[i] = *(const u16x8*)(src + i * 8);
    float ss = 0.f;
    #pragma unroll
    for (int i = 0; i < 9; i++)
      #pragma unroll
      for (int e = 0; e < 8; e++){ float f = bf2f(xr[i][e]); ss += f * f; }
    float rs_ = rsqrtf(ss * (1.f / 72.f) + 1e-6f);
    float x[72];
    #pragma unroll
    for (int i = 0; i < 9; i++)
      #pragma unroll
      for (int e = 0; e < 8; e++){ int d = i * 8 + e; x[d] = bf2f(xr[i][e]) * rs_ * sc[d]; }
    #pragma unroll
    for (int c = 0; c < 2; c++)
      #pragma unroll
      for (int j = 0; j < 18; j++){
        float co = tc[(size_t)tok * 36 + c * 18 + j];
        float si = ts[(size_t)tok * 36 + c * 18 + j];
        float x1 = x[c * 36 + j], x2 = x[c * 36 + j + 18];
        x[c * 36 + j]      = x1 * co - x2 * si;
        x[c * 36 + j + 18] = x2 * co + x1 * si;
      }
    size_t off = ((size_t)bh * 1024 + n) * DPAD;
    #pragma unroll
    for (int i = 0; i < 9; i++){
      u16x8 o;
      #pragma unroll
      for (int e = 0; e < 8; e++) o[e] = f2bf(x[i * 8 + e] * fold);
      *(u16x8*)(dst + off + i * 8) = o;
    }
    u16x8 z = {0,0,0,0,0,0,0,0};
    #pragma unroll
    for (int i = 9; i < 12; i++) *(u16x8*)(dst + off + i * 8) = z;
  }
  __syncthreads();
  u16x8 z = {0,0,0,0,0,0,0,0};
  u16x8 on = {0x3F80,0x3F80,0x3F80,0x3F80,0x3F80,0x3F80,0x3F80,0x3F80};
  for (int c = tid; c < VROWS * 32; c += 256){
    int row = c >> 5, seg = c & 31;
    u16x8 v;
    if (row < 72)       v = *(const u16x8*)&vl[row][seg * 8];
    else if (row == 72) v = on;
    else                v = z;
    *(u16x8*)(Vt + ((size_t)bh * VROWS + row) * 1024 + n0 + seg * 8) = v;
  }
}

// --- flash attention, 8 waves x 32 q, no-max softmax, K/V prefetch  ----
// T14 async-split: tile kv+1 global->reg issued after opening barrier,
// ds_write at top of next iter. Raw s_barrier (no vmcnt drain) keeps the
// prefetch in flight. Pl stride 76 kills the 4-way P-write conflict.
__global__ __launch_bounds__(512, 4) void attn(const u16* __restrict__ Qp, const u16* __restrict__ Kp,
                                               const u16* __restrict__ Vt, u16* __restrict__ AO){
  __shared__ u16 Kl[64][104];        // 208B stride
  __shared__ u16 Vl[VROWS][72];      // 144B stride
  __shared__ u16 Pl[8][32][76];      // 152B stride: write banks {0,24,16,8}
  int tid = threadIdx.x, lane = tid & 63, w = tid >> 6;
  int l16 = lane & 15, lq = lane >> 4;
  int bh = blockIdx.y, b = bh >> 4, h = bh & 15;
  int q0 = blockIdx.x * 256;
  const u16* Qb = Qp + (size_t)bh * 1024 * DPAD;
  const u16* Kb = Kp + (size_t)bh * 1024 * DPAD;
  const u16* Vb = Vt + (size_t)bh * VROWS * 1024;

  // staging maps (wave-uniform predicates: tid<256 = waves 0-3, tid<128 = waves 0-1)
  int krow0 = tid / 12, kcol0 = tid - krow0 * 12;
  int kc1 = tid + 512;  int krow1 = kc1 / 12, kcol1 = kc1 - krow1 * 12;
  int vrow0 = tid >> 3, vseg0 = tid & 7;
  int vc1 = tid + 512;  int vrow1 = vc1 >> 3, vseg1 = vc1 & 7;

  bf16x8 qf[2][3];
  #pragma unroll
  for (int mt = 0; mt < 2; mt++)
    #pragma unroll
    for (int ks = 0; ks < 3; ks++)
      qf[mt][ks] = *(const bf16x8*)(Qb + (size_t)(q0 + w * 32 + mt * 16 + l16) * DPAD + ks * 32 + lq * 8);

  f32x4 accO[2][5] = {};
  u16x8 kp0, kp1, vp0, vp1;
  kp0 = *(const u16x8*)(Kb + (size_t)krow0 * DPAD + kcol0 * 8);
  if (tid < 256) kp1 = *(const u16x8*)(Kb + (size_t)krow1 * DPAD + kcol1 * 8);
  vp0 = *(const u16x8*)(Vb + (size_t)vrow0 * 1024 + vseg0 * 8);
  if (tid < 128) vp1 = *(const u16x8*)(Vb + (size_t)vrow1 * 1024 + vseg1 * 8);

  for (int kv = 0; kv < 16; ++kv){
    *(u16x8*)&Kl[krow0][kcol0 * 8] = kp0;
    if (tid < 256) *(u16x8*)&Kl[krow1][kcol1 * 8] = kp1;
    *(u16x8*)&Vl[vrow0][vseg0 * 8] = vp0;
    if (tid < 128) *(u16x8*)&Vl[vrow1][vseg1 * 8] = vp1;
    LGK0; BARX();                                  // writes visible; no vmcnt drain
    if (kv < 15){                                  // prefetch tile kv+1 during compute
      const u16* Kn = Kb + (size_t)(kv + 1) * 64 * DPAD;
      const u16* Vn = Vb + (size_t)(kv + 1) * 64;
      kp0 = *(const u16x8*)(Kn + (size_t)krow0 * DPAD + kcol0 * 8);
      if (tid < 256) kp1 = *(const u16x8*)(Kn + (size_t)krow1 * DPAD + kcol1 * 8);
      vp0 = *(const u16x8*)(Vn + (size_t)vrow0 * 1024 + vseg0 * 8);
      if (tid < 128) vp1 = *(const u16x8*)(Vn + (size_t)vrow1 * 1024 + vseg1 * 8);
    }

    f32x4 accS[2][4] = {};
    #pragma unroll
    for (int j = 0; j < 4; j++)
      #pragma unroll
      for (int ks = 0; ks < 3; ks++){
        bf16x8 kf = *(const bf16x8*)&Kl[j * 16 + l16][ks * 32 + lq * 8];
        accS[0][j] = __builtin_amdgcn_mfma_f32_16x16x32_bf16(qf[0][ks], kf, accS[0][j], 0, 0, 0);
        accS[1][j] = __builtin_amdgcn_mfma_f32_16x16x32_bf16(qf[1][ks], kf, accS[1][j], 0, 0, 0);
      }
    #pragma unroll
    for (int mt = 0; mt < 2; mt++)
      #pragma unroll
      for (int j = 0; j < 4; j++)
        #pragma unroll
        for (int r = 0; r < 4; r++)
          Pl[w][mt * 16 + lq * 4 + r][j * 16 + l16] = f2bf(exp2f(accS[mt][j][r]));
    #pragma unroll
    for (int ks = 0; ks < 2; ks++){
      bf16x8 pf0 = *(const bf16x8*)&Pl[w][l16][ks * 32 + lq * 8];
      bf16x8 pf1 = *(const bf16x8*)&Pl[w][16 + l16][ks * 32 + lq * 8];
      #pragma unroll
      for (int nf = 0; nf < 5; nf++){
        bf16x8 vf = *(const bf16x8*)&Vl[nf * 16 + l16][ks * 32 + lq * 8];
        accO[0][nf] = __builtin_amdgcn_mfma_f32_16x16x32_bf16(pf0, vf, accO[0][nf], 0, 0, 0);
        accO[1][nf] = __builtin_amdgcn_mfma_f32_16x16x32_bf16(pf1, vf, accO[1][nf], 0, 0, 0);
      }
    }
    BARX();                                        // all LDS reads done (per-wave data deps)
  }
  #pragma unroll
  for (int mt = 0; mt < 2; mt++)
    #pragma unroll
    for (int r = 0; r < 4; r++){
      float s = __shfl(accO[mt][4][r], (lane & 48) + 8);   // col 72 = denominator
      float inv = 1.f / s;
      int qg = q0 + w * 32 + mt * 16 + lq * 4 + r;
      size_t rowoff = ((size_t)(b * 1024 + qg)) * DMODEL + h * DHEAD;
      #pragma unroll
      for (int nf = 0; nf < 5; nf++){
        int d = nf * 16 + l16;
        if (d < 72) AO[rowoff + d] = f2bf(accO[mt][nf][r] * inv);
      }
    }
}

extern "C" void kernel_launch(void* const* d_in, const int* in_sizes, int n_in,
                              void* d_out, int out_size, void* d_ws, size_t ws_size,
                              hipStream_t stream){
  const float* X   = (const float*)d_in[0];
  const int*   pid = (const int*)  d_in[1];
  const float* Wq  = (const float*)d_in[2];
  const float* Wk  = (const float*)d_in[3];
  const float* Wv  = (const float*)d_in[4];
  const float* Wo  = (const float*)d_in[5];
  const float* qsc = (const float*)d_in[6];
  const float* ksc = (const float*)d_in[7];
  const float* vsc = (const float*)d_in[8];
  char* ws = (char*)d_ws;
  u16*   Xb  = (u16*)(ws);                    // 18,874,368
  u16*   WT  = (u16*)(ws + 18874368);         // 10,616,832
  u16*   QKV = (u16*)(ws + 29491200);         // 56,623,104
  u16*   Qp  = (u16*)(ws + 86114304);         // 25,165,824
  u16*   Kp  = (u16*)(ws + 111280128);        // 25,165,824
  u16*   Vt  = (u16*)(ws + 136445952);        // 20,971,520
  float* tc  = (float*)(ws + 157417472);      // 1,179,648
  float* tsn = (float*)(ws + 158597120);      // 1,179,648
  u16*   AO  = QKV;                           // alias: QKV dead after rmsrope

  prep   <<<10944, 256, 0, stream>>>(X, Xb, Wq, Wk, Wv, Wo, WT, pid, tc, tsn);
  gemm256<<<448, 512, 0, stream>>>(Xb, WT, QKV);
  rmsrope<<<dim3(32, 16), 256, 0, stream>>>(QKV, tc, tsn, qsc, ksc, vsc, Qp, Kp, Vt);
  attn   <<<dim3(4, 128), 512, 0, stream>>>(Qp, Kp, Vt, AO);
  gemm_bt<1><<<dim3(64, 9), 256, 0, stream>>>(AO, WT + (size_t)3456 * 1152, d_out, 1152);
}